// Round 1
// baseline (950.768 us; speedup 1.0000x reference)
//
#include <hip/hip_runtime.h>

#define FIN 512
#define FMID 16
#define FOUT 64

__global__ void k_deg_init(float* __restrict__ deg, int n) {
  int i = blockIdx.x * blockDim.x + threadIdx.x;
  if (i < n) deg[i] = 1.0f;  // self-loop contribution
}

__global__ void k_deg_edges(const int* __restrict__ dst, float* __restrict__ deg, int E) {
  int e = blockIdx.x * blockDim.x + threadIdx.x;
  if (e < E) atomicAdd(&deg[dst[e]], 1.0f);
}

__global__ void k_deg_finish(float* __restrict__ deg, int n) {
  int i = blockIdx.x * blockDim.x + threadIdx.x;
  if (i < n) deg[i] = rsqrtf(deg[i]);  // deg >= 1 always (self-loop)
}

// h[node, 0:16] = x[node, 0:512] @ W1. One wave per node: lane = q*16+j,
// quarter q covers k in [q*128, q*128+128), lane j accumulates output j.
// W1 staged in LDS; reads w[k*16+j] are 16 consecutive words replicated
// across 4 quarters -> 4-way bank conflict (1.58x, acceptable).
__global__ __launch_bounds__(256) void k_gemm1(const float* __restrict__ x,
                                               const float* __restrict__ W1,
                                               float* __restrict__ h, int n) {
  __shared__ float w[FIN * FMID];  // 32 KB
  for (int idx = threadIdx.x; idx < FIN * FMID; idx += 256) w[idx] = W1[idx];
  __syncthreads();
  const int lane = threadIdx.x & 63;
  const int q = lane >> 4, j = lane & 15;
  const int node = blockIdx.x * 4 + (threadIdx.x >> 6);
  if (node >= n) return;
  const float4* xr = (const float4*)(x + (size_t)node * FIN + q * 128);
  float acc = 0.f;
#pragma unroll
  for (int t4 = 0; t4 < 32; ++t4) {
    float4 xv = xr[t4];
    int k = q * 128 + t4 * 4;
    acc += xv.x * w[(k + 0) * FMID + j];
    acc += xv.y * w[(k + 1) * FMID + j];
    acc += xv.z * w[(k + 2) * FMID + j];
    acc += xv.w * w[(k + 3) * FMID + j];
  }
  // reduce across the 4 quarters (lanes j, j+16, j+32, j+48)
  acc += __shfl_xor(acc, 16);
  acc += __shfl_xor(acc, 32);
  if (lane < FMID) h[(size_t)node * FMID + j] = acc;
}

// a[i,j] = h[i,j] * dis[i]^2   (self-loop message; also zero-initializes a)
__global__ void k_selfloop(const float* __restrict__ h, const float* __restrict__ dis,
                           float* __restrict__ a, int total16) {
  int t = blockIdx.x * blockDim.x + threadIdx.x;
  if (t < total16) {
    float d = dis[t >> 4];
    a[t] = h[t] * d * d;
  }
}

// a[dst, j] += h[src, j] * dis[src]*dis[dst]; 16 lanes per edge.
__global__ void k_prop(const float* __restrict__ h, const int* __restrict__ src,
                       const int* __restrict__ dst, const float* __restrict__ dis,
                       float* __restrict__ out, int E) {
  int t = blockIdx.x * blockDim.x + threadIdx.x;
  int e = t >> 4;
  if (e >= E) return;
  int jj = t & 15;
  int s = src[e], d = dst[e];
  float norm = dis[s] * dis[d];
  atomicAdd(&out[(size_t)d * FMID + jj], h[(size_t)s * FMID + jj] * norm);
}

__global__ void k_bias_relu(float* __restrict__ a, const float* __restrict__ b, int total16) {
  int t = blockIdx.x * blockDim.x + threadIdx.x;
  if (t < total16) {
    float v = a[t] + b[t & 15];
    a[t] = v > 0.f ? v : 0.f;
  }
}

// out[node, 0:64] = log_softmax(a2[node, 0:16] @ W2 + b2). One wave per node,
// lane = output feature; max/sum via 64-lane butterfly shuffles.
__global__ __launch_bounds__(256) void k_out(const float* __restrict__ a2,
                                             const float* __restrict__ W2,
                                             const float* __restrict__ b2,
                                             float* __restrict__ out, int n) {
  __shared__ float w[FMID * FOUT];  // 4 KB
  for (int idx = threadIdx.x; idx < FMID * FOUT; idx += 256) w[idx] = W2[idx];
  __syncthreads();
  const int lane = threadIdx.x & 63;
  const int node = blockIdx.x * 4 + (threadIdx.x >> 6);
  if (node >= n) return;
  const float* ar = a2 + (size_t)node * FMID;
  float o = b2[lane];
#pragma unroll
  for (int k = 0; k < FMID; ++k) o += ar[k] * w[k * FOUT + lane];
  float m = o;
#pragma unroll
  for (int off = 32; off >= 1; off >>= 1) m = fmaxf(m, __shfl_xor(m, off));
  float e = __expf(o - m);
  float s = e;
#pragma unroll
  for (int off = 32; off >= 1; off >>= 1) s += __shfl_xor(s, off);
  out[(size_t)node * FOUT + lane] = o - m - __logf(s);
}

extern "C" void kernel_launch(void* const* d_in, const int* in_sizes, int n_in,
                              void* d_out, int out_size, void* d_ws, size_t ws_size,
                              hipStream_t stream) {
  const float* x  = (const float*)d_in[0];
  const int* edge = (const int*)d_in[1];
  const float* W1 = (const float*)d_in[2];
  const float* b1 = (const float*)d_in[3];
  const float* W2 = (const float*)d_in[4];
  const float* b2 = (const float*)d_in[5];
  float* out = (float*)d_out;

  const int N = in_sizes[0] / FIN;   // 100000
  const int E = in_sizes[1] / 2;     // 3200000
  const int* src = edge;
  const int* dst = edge + E;

  // workspace layout (floats): dis[N] | h[16N] | a1[16N] | a2[16N]  = 49N ~ 19.6 MB
  float* f   = (float*)d_ws;
  float* dis = f;
  float* h   = f + (size_t)N;
  float* a1  = f + 17 * (size_t)N;
  float* a2  = f + 33 * (size_t)N;

  const int T = 256;
  const int t16n = N * FMID;
  const long te = (long)E * FMID;

  k_deg_init  <<<(N + T - 1) / T, T, 0, stream>>>(dis, N);
  k_deg_edges <<<(E + T - 1) / T, T, 0, stream>>>(dst, dis, E);
  k_deg_finish<<<(N + T - 1) / T, T, 0, stream>>>(dis, N);

  k_gemm1     <<<(N + 3) / 4, T, 0, stream>>>(x, W1, h, N);

  // layer 1 propagate (16-dim)
  k_selfloop  <<<(t16n + T - 1) / T, T, 0, stream>>>(h, dis, a1, t16n);
  k_prop      <<<(int)((te + T - 1) / T), T, 0, stream>>>(h, src, dst, dis, a1, E);
  k_bias_relu <<<(t16n + T - 1) / T, T, 0, stream>>>(a1, b1, t16n);

  // layer 2 propagate FIRST at 16-dim (P(h1 W2) == (P h1) W2), then transform
  k_selfloop  <<<(t16n + T - 1) / T, T, 0, stream>>>(a1, dis, a2, t16n);
  k_prop      <<<(int)((te + T - 1) / T), T, 0, stream>>>(a1, src, dst, dis, a2, E);

  k_out       <<<(N + 3) / 4, T, 0, stream>>>(a2, W2, b2, out, N);
}